// Round 1
// baseline (274.087 us; speedup 1.0000x reference)
//
#include <hip/hip_runtime.h>
#include <hip/hip_bf16.h>

// Problem: n=8192 rows, d=256 features, 10 classes.
// loss = mean_i log1p(exp(0.5/0.7) * A_i * B_i)
//   A_i = sum_{j: y_j != y_i} exp(sim_ij / 0.7)        (or 1.0 if empty)
//   B_i = sum_{j != i: y_j == y_i} exp(-sim_ij / 0.7)  (or 1.0 if empty)
//   sim = normalize_rows(P) @ normalize_rows(P)^T
//
// Strategy: bf16 MFMA 16x16x32 GEMM, 128x128 block tile, 4 waves of 64x64,
// fused epilogue (exp + class mask + row-sum + atomicAdd). sim never hits
// memory. ws usage: 4MB bf16 P + 2*32KB row accumulators + 256B histogram.

#define NF 256            // feature dim
#define TEMP_INV (1.0f / 0.7f)
#define LDA 72            // LDS row stride in bf16 elems (64 + 8 pad -> 144B)

typedef __attribute__((ext_vector_type(8))) short short8;
typedef __attribute__((ext_vector_type(4))) float float4v;

__global__ void k_rownorm(const float* __restrict__ P, unsigned short* __restrict__ Pn) {
    int row = blockIdx.x;
    int t = threadIdx.x;  // 256 threads, one per feature
    float v = P[(size_t)row * NF + t];
    float sq = v * v;
#pragma unroll
    for (int off = 32; off > 0; off >>= 1) sq += __shfl_xor(sq, off, 64);
    __shared__ float red[4];
    if ((t & 63) == 0) red[t >> 6] = sq;
    __syncthreads();
    float tot = red[0] + red[1] + red[2] + red[3];
    __hip_bfloat16 h = __float2bfloat16(v * rsqrtf(tot));
    Pn[(size_t)row * NF + t] = *(unsigned short*)&h;
}

__global__ void k_hist(const int* __restrict__ y, int* __restrict__ hist, int n) {
    int i = blockIdx.x * blockDim.x + threadIdx.x;
    if (i < n) atomicAdd(&hist[y[i] & 63], 1);
}

__global__ __launch_bounds__(256)
void k_main(const unsigned short* __restrict__ Pn, const int* __restrict__ y,
            float* __restrict__ Aacc, float* __restrict__ Bacc) {
    __shared__ __align__(16) unsigned short As[128 * LDA];
    __shared__ __align__(16) unsigned short Bs[128 * LDA];
    __shared__ int yr[128], yc[128];

    const int tid = threadIdx.x;
    const int lane = tid & 63, wave = tid >> 6;
    const int quad = lane >> 4, l15 = lane & 15;
    const int wr = wave >> 1, wc = wave & 1;     // 2x2 wave grid, 64x64 each
    const int rb = blockIdx.y * 128, cb = blockIdx.x * 128;

    if (tid < 128) yr[tid] = y[rb + tid];
    else           yc[tid - 128] = y[cb + tid - 128];

    float4v acc[4][4];
#pragma unroll
    for (int a = 0; a < 4; ++a)
#pragma unroll
        for (int b = 0; b < 4; ++b) acc[a][b] = (float4v){0.f, 0.f, 0.f, 0.f};

    for (int k0 = 0; k0 < NF; k0 += 64) {
        if (k0) __syncthreads();  // protect LDS reuse
        uint4 va[4], vb[4];
#pragma unroll
        for (int p = 0; p < 4; ++p) {
            int s = p * 256 + tid;              // 1024 segs of 8 bf16 per panel
            int row = s >> 3, sc = s & 7;
            va[p] = *(const uint4*)(Pn + (size_t)(rb + row) * NF + k0 + sc * 8);
            vb[p] = *(const uint4*)(Pn + (size_t)(cb + row) * NF + k0 + sc * 8);
        }
#pragma unroll
        for (int p = 0; p < 4; ++p) {
            int s = p * 256 + tid;
            int row = s >> 3, sc = s & 7;
            *(uint4*)&As[row * LDA + sc * 8] = va[p];
            *(uint4*)&Bs[row * LDA + sc * 8] = vb[p];
        }
        __syncthreads();
#pragma unroll
        for (int ks = 0; ks < 2; ++ks) {        // two k=32 sub-steps
            short8 af[4], bf4[4];
#pragma unroll
            for (int t = 0; t < 4; ++t) {
                af[t]  = *(const short8*)&As[(wr * 64 + t * 16 + l15) * LDA + ks * 32 + quad * 8];
                bf4[t] = *(const short8*)&Bs[(wc * 64 + t * 16 + l15) * LDA + ks * 32 + quad * 8];
            }
#pragma unroll
            for (int tr = 0; tr < 4; ++tr)
#pragma unroll
                for (int tc = 0; tc < 4; ++tc)
                    acc[tr][tc] = __builtin_amdgcn_mfma_f32_16x16x32_bf16(
                        af[tr], bf4[tc], acc[tr][tc], 0, 0, 0);
        }
    }

    // Epilogue: C/D layout col=lane&15, row=quad*4+reg.
#pragma unroll
    for (int tr = 0; tr < 4; ++tr) {
        float as4[4] = {0.f, 0.f, 0.f, 0.f}, bs4[4] = {0.f, 0.f, 0.f, 0.f};
        int yi4[4];
#pragma unroll
        for (int r = 0; r < 4; ++r) yi4[r] = yr[wr * 64 + tr * 16 + quad * 4 + r];
#pragma unroll
        for (int tc = 0; tc < 4; ++tc) {
            int jl = wc * 64 + tc * 16 + l15;
            int yj = yc[jl];
            int gj = cb + jl;
#pragma unroll
            for (int r = 0; r < 4; ++r) {
                float s = acc[tr][tc][r];
                bool same = (yi4[r] == yj);
                float e = __expf((same ? -s : s) * TEMP_INV);
                int gi = rb + wr * 64 + tr * 16 + quad * 4 + r;
                if (same) { if (gi != gj) bs4[r] += e; }
                else      { as4[r] += e; }
            }
        }
#pragma unroll
        for (int r = 0; r < 4; ++r) {
#pragma unroll
            for (int off = 1; off < 16; off <<= 1) {
                as4[r] += __shfl_xor(as4[r], off, 64);
                bs4[r] += __shfl_xor(bs4[r], off, 64);
            }
        }
        if (l15 == 0) {
#pragma unroll
            for (int r = 0; r < 4; ++r) {
                int gi = rb + wr * 64 + tr * 16 + quad * 4 + r;
                atomicAdd(&Aacc[gi], as4[r]);
                atomicAdd(&Bacc[gi], bs4[r]);
            }
        }
    }
}

__global__ void k_final(const float* __restrict__ Aacc, const float* __restrict__ Bacc,
                        const int* __restrict__ y, const int* __restrict__ hist,
                        float* __restrict__ out, int n) {
    float s = 0.f;
    const float M = __expf(0.5f * TEMP_INV);
    for (int i = threadIdx.x; i < n; i += 256) {
        int c = hist[y[i] & 63];
        float a = (n - c) > 0 ? Aacc[i] : 1.0f;
        float b = (c - 1) > 0 ? Bacc[i] : 1.0f;
        s += log1pf(M * a * b);
    }
#pragma unroll
    for (int off = 32; off > 0; off >>= 1) s += __shfl_xor(s, off, 64);
    __shared__ float red[4];
    if ((threadIdx.x & 63) == 0) red[threadIdx.x >> 6] = s;
    __syncthreads();
    if (threadIdx.x == 0) out[0] = (red[0] + red[1] + red[2] + red[3]) / (float)n;
}

extern "C" void kernel_launch(void* const* d_in, const int* in_sizes, int n_in,
                              void* d_out, int out_size, void* d_ws, size_t ws_size,
                              hipStream_t stream) {
    const float* P = (const float*)d_in[0];
    const int* y   = (const int*)d_in[1];
    float* out     = (float*)d_out;
    const int n = in_sizes[1];  // 8192

    // ws layout: Pn bf16 [n*256] | Aacc f32 [n] | Bacc f32 [n] | hist i32 [64]
    unsigned short* Pn = (unsigned short*)d_ws;
    float* Aacc = (float*)((char*)d_ws + (size_t)n * NF * 2);
    float* Bacc = Aacc + n;
    int* hist   = (int*)(Bacc + n);

    hipMemsetAsync(Aacc, 0, (size_t)2 * n * sizeof(float) + 64 * sizeof(int), stream);
    k_rownorm<<<n, 256, 0, stream>>>(P, Pn);
    k_hist<<<n / 256, 256, 0, stream>>>(y, hist, n);
    dim3 grid(n / 128, n / 128);
    k_main<<<grid, 256, 0, stream>>>(Pn, y, Aacc, Bacc);
    k_final<<<1, 256, 0, stream>>>(Aacc, Bacc, y, hist, out, n);
}